// Round 1
// baseline (110.777 us; speedup 1.0000x reference)
//
#include <hip/hip_runtime.h>
#include <stdint.h>
#include <math.h>

#define N     500
#define DIN   100
#define DE    200
#define DOUT  100
#define AROW  (2*DIN + DE)        // 400
#define NEG_BIG (-9000000000000000.0f)
#define SLOPE 0.2f

#define JT     32                 // j-tile rows
#define KSTEPS 13                 // ceil(208/16): K padded 200 -> 208
#define ROWB   512                // LDS bytes per tile row (swizzle-safe, 256 bf16)
#define NTILES ((N + JT - 1) / JT)  // 16

typedef __attribute__((ext_vector_type(8)))  short short8;
typedef __attribute__((ext_vector_type(16))) float f32x16;

static __device__ __forceinline__ unsigned short f2bf(float f) {
  union { float f; uint32_t u; } v; v.f = f;
  uint32_t r = (v.u + 0x7FFFu + ((v.u >> 16) & 1u)) >> 16;   // RNE
  return (unsigned short)r;
}

// ---------------- kernel 1a: src, dst, ssrc, sdst ----------------
__global__ void precompute_kernel(const float* __restrict__ R,
                                  const float* __restrict__ A,
                                  const float* __restrict__ a2,
                                  float* __restrict__ src, float* __restrict__ dst,
                                  float* __restrict__ ssrc, float* __restrict__ sdst) {
  int i = blockIdx.x;
  int t = threadIdx.x;
  __shared__ float rrow[DIN];
  __shared__ float red[256];
  if (t < DIN) rrow[t] = R[i * DIN + t];
  __syncthreads();
  int o = -1; bool isSrc = false;
  if (t < DOUT) { o = t; isSrc = true; }
  else if (t >= 128 && t < 128 + DOUT) { o = t - 128; }
  float val = 0.f;
  if (o >= 0) {
    const float* arow = A + o * AROW + (isSrc ? 0 : DIN);
    #pragma unroll 4
    for (int d = 0; d < DIN; ++d) val += rrow[d] * arow[d];
    if (isSrc) src[i * DOUT + o] = val; else dst[i * DOUT + o] = val;
    red[t] = val * a2[o];
  } else red[t] = 0.f;
  __syncthreads();
  if (t == 0) { float s = 0; for (int k = 0; k < DOUT; ++k) s += red[k];       ssrc[i] = s; }
  if (t == 1) { float s = 0; for (int k = 0; k < DOUT; ++k) s += red[128 + k]; sdst[i] = s; }
}

// ---------------- kernel 1b: w[d] = sum_o a_ent[o,d]*a2[o] ----------------
__global__ void wvec_kernel(const float* __restrict__ A, const float* __restrict__ a2,
                            float* __restrict__ w) {
  int d = threadIdx.x;
  if (d < DE) {
    float s = 0.f;
    for (int o = 0; o < DOUT; ++o) s += A[o * AROW + 2 * DIN + d] * a2[o];
    w[d] = s;
  }
}

// ---------------- main fused kernel: one WG per row i ----------------
__global__ __launch_bounds__(256, 2)
void gat_main(const float* __restrict__ E, const int* __restrict__ adj,
              const float* __restrict__ A,
              const float* __restrict__ src, const float* __restrict__ dst,
              const float* __restrict__ ssrcA, const float* __restrict__ sdstA,
              const float* __restrict__ wv, float* __restrict__ out) {
  __shared__ uint64_t lds64[JT * ROWB / 8];   // 16 KiB E tile (bf16, swizzled)
  __shared__ float e2raw[JT];
  char* ldsE = (char*)lds64;

  int i    = blockIdx.x;
  int t    = threadIdx.x;
  int wave = t >> 6;
  int lane = t & 63;
  int c31  = lane & 31;
  int hi   = lane >> 5;
  int o    = wave * 32 + c31;          // 0..127 (pad >= 100)
  int oc   = o < DOUT ? o : DOUT - 1;
  bool ovalid = (o < DOUT);

  // B fragments: B[k=d][n=o] = a_ent[o,d]; wave3 col4 carries w[d]
  short8 bfrag[KSTEPS];
  #pragma unroll
  for (int k = 0; k < KSTEPS; ++k) {
    int d0 = k * 16 + hi * 8;
    float f[8];
    if (d0 + 8 <= DE) {
      if (ovalid) {
        const float* p = A + o * AROW + 2 * DIN + d0;
        #pragma unroll
        for (int e = 0; e < 8; ++e) f[e] = p[e];
      } else if (wave == 3 && c31 == 4) {
        #pragma unroll
        for (int e = 0; e < 8; ++e) f[e] = wv[d0 + e];
      } else {
        #pragma unroll
        for (int e = 0; e < 8; ++e) f[e] = 0.f;
      }
    } else {
      #pragma unroll
      for (int e = 0; e < 8; ++e) f[e] = 0.f;
    }
    short8 s;
    #pragma unroll
    for (int e = 0; e < 8; ++e) s[e] = (short)f2bf(f[e]);
    bfrag[k] = s;
  }

  float ssrc_i = ssrcA[i];
  const float* Erow = E + (size_t)i * N * DE;

  float m = -__builtin_inff();
  float Z = 0.f;
  float hacc = 0.f;

  for (int tile = 0; tile < NTILES; ++tile) {
    int j0 = tile * JT;
    __syncthreads();
    // ---- stage E tile -> LDS bf16, XOR-swizzled (bits 4..8 ^ row<<4) ----
    for (int f4 = t; f4 < JT * 50; f4 += 256) {
      int row  = f4 / 50;
      int col4 = f4 % 50;
      int j = j0 + row;
      float4 v;
      if (j < N) v = *(const float4*)(Erow + (size_t)j * DE + col4 * 4);
      else       v = make_float4(0.f, 0.f, 0.f, 0.f);
      ushort4 pk;
      pk.x = f2bf(v.x); pk.y = f2bf(v.y); pk.z = f2bf(v.z); pk.w = f2bf(v.w);
      int c = col4 * 8;
      int addr = row * ROWB + (c ^ ((row & 31) << 4));
      *(ushort4*)(ldsE + addr) = pk;
    }
    if (t < 64) {  // zero-pad d = 200..207
      int row = t >> 1;
      int c = 400 + (t & 1) * 8;
      int addr = row * ROWB + (c ^ ((row & 31) << 4));
      *(uint64_t*)(ldsE + addr) = 0ull;
    }
    __syncthreads();

    // ---- MFMA: acc[m=j, n=o] over K=208 ----
    f32x16 acc = {};
    #pragma unroll
    for (int k = 0; k < KSTEPS; ++k) {
      int row = c31;
      int c = k * 32 + hi * 16;
      int addr = row * ROWB + (c ^ ((row & 31) << 4));
      short8 af = *(const short8*)(ldsE + addr);
      acc = __builtin_amdgcn_mfma_f32_32x32x16_bf16(af, bfrag[k], acc, 0, 0, 0);
    }

    // wave3 col4 = E·w per row -> e2raw
    if (wave == 3 && c31 == 4) {
      #pragma unroll
      for (int r = 0; r < 16; ++r) {
        int row = (r & 3) + 8 * (r >> 2) + 4 * hi;
        e2raw[row] = acc[r];
      }
    }
    __syncthreads();

    // ---- scores + online softmax + h accumulation ----
    float s[16];
    float mt = -__builtin_inff();
    #pragma unroll
    for (int r = 0; r < 16; ++r) {
      int row = (r & 3) + 8 * (r >> 2) + 4 * hi;
      int j = j0 + row;
      float sv;
      if (j < N) {
        float e2 = ssrc_i + sdstA[j] + e2raw[row];
        e2 = e2 > 0.f ? e2 : SLOPE * e2;
        sv = (adj[(size_t)i * N + j] > 0) ? e2 : NEG_BIG;
      } else sv = -__builtin_inff();
      s[r] = sv;
      mt = fmaxf(mt, sv);
    }
    mt = fmaxf(mt, __shfl_xor(mt, 32, 64));
    float mnew  = fmaxf(m, mt);
    float scale = __expf(m - mnew);       // m=-inf first tile -> 0
    float psum = 0.f, hadd = 0.f;
    #pragma unroll
    for (int r = 0; r < 16; ++r) {
      int row = (r & 3) + 8 * (r >> 2) + 4 * hi;
      int j = j0 + row;
      int jc = j < N ? j : N - 1;
      float pv = __expf(s[r] - mnew);     // 0 for pad / strongly-masked
      psum += pv;
      float eprime = acc[r] + dst[jc * DOUT + oc];   // ent + dst[j,o]
      hadd += pv * eprime;
    }
    psum += __shfl_xor(psum, 32, 64);
    Z    = Z * scale + psum;
    hacc = hacc * scale + hadd;
    m = mnew;
  }

  // ---- epilogue: combine halves, add src, normalize, elu ----
  hacc += __shfl_xor(hacc, 32, 64);
  if (hi == 0 && ovalid) {
    float h = src[i * DOUT + o] + hacc / Z;
    out[i * DOUT + o] = h > 0.f ? h : expm1f(h);
  }
}

extern "C" void kernel_launch(void* const* d_in, const int* in_sizes, int n_in,
                              void* d_out, int out_size, void* d_ws, size_t ws_size,
                              hipStream_t stream) {
  const float* R   = (const float*)d_in[0];
  const float* E   = (const float*)d_in[1];
  const int*   adj = (const int*)d_in[2];
  const float* A   = (const float*)d_in[3];
  const float* a2  = (const float*)d_in[4];
  float* out = (float*)d_out;

  float* ws   = (float*)d_ws;
  float* src  = ws;                       // N*DOUT
  float* dst  = ws + N * DOUT;            // N*DOUT
  float* ssrc = ws + 2 * N * DOUT;        // N
  float* sdst = ssrc + N;                 // N
  float* wv   = sdst + N;                 // DE

  precompute_kernel<<<N, 256, 0, stream>>>(R, A, a2, src, dst, ssrc, sdst);
  wvec_kernel<<<1, 256, 0, stream>>>(A, a2, wv);
  gat_main<<<N, 256, 0, stream>>>(E, adj, A, src, dst, ssrc, sdst, wv, out);
}